// Round 9
// baseline (4660.812 us; speedup 1.0000x reference)
//
#include <hip/hip_runtime.h>
#include <hip/hip_bf16.h>
#include <math.h>

// HAN: word bi-GRU + attention -> sentence bi-GRU + attention -> doc vector.
// R9: ABLATION ROUND. word_rnn gains (mode, nsteps, hread) params:
//   mode 0: barrier only            (32 steps, reads/writes nothing)
//   mode 1: + K-loop + st_coh store (32 steps, h-pattern reads from xWt)
//   mode 2: full/real               (96 steps, h state in bi)  <- output path
// Everything else identical to R8.

typedef __attribute__((ext_vector_type(8))) short short8;
typedef __attribute__((ext_vector_type(4))) float f32x4;

__device__ __forceinline__ unsigned short f2bf(float f) {
    unsigned int u = __float_as_uint(f);
    u += 0x7fff + ((u >> 16) & 1);   // RNE
    return (unsigned short)(u >> 16);
}
__device__ __forceinline__ float bf2f(unsigned short u) {
    return __uint_as_float(((unsigned int)u) << 16);
}
__device__ __forceinline__ float sigmoidf_(float x) { return 1.f / (1.f + expf(-x)); }

__device__ __forceinline__ f32x4 mfma16(short8 a, short8 b, f32x4 c) {
    return __builtin_amdgcn_mfma_f32_16x16x32_bf16(a, b, c, 0, 0, 0);
}

// trunc-split 8 f32 -> hi/lo bf16 short8 (pure bit ops)
__device__ __forceinline__ void split_win(f32x4 a, f32x4 b, short8* hv, short8* lv) {
    union { short8 s; unsigned u[4]; } H, L;
#pragma unroll
    for (int d = 0; d < 4; d++) {
        float f0 = (d < 2) ? a[2 * d] : b[2 * d - 4];
        float f1 = (d < 2) ? a[2 * d + 1] : b[2 * d - 3];
        unsigned u0 = __float_as_uint(f0), u1 = __float_as_uint(f1);
        H.u[d] = (u1 & 0xffff0000u) | (u0 >> 16);
        float l0 = f0 - __uint_as_float(u0 & 0xffff0000u);
        float l1 = f1 - __uint_as_float(u1 & 0xffff0000u);
        L.u[d] = (__float_as_uint(l1) & 0xffff0000u) | (__float_as_uint(l0) >> 16);
    }
    *hv = H.s; *lv = L.s;
}

// coherent (IF-direct) f32 store, relaxed
__device__ __forceinline__ void st_coh(float* p, float v) {
    __hip_atomic_store((unsigned*)p, __float_as_uint(v),
                       __ATOMIC_RELAXED, __HIP_MEMORY_SCOPE_AGENT);
}

// Grid barrier: monotonic hierarchical counters, all relaxed, no cache ops.
__device__ __forceinline__ void gbar(unsigned* cnt1, unsigned* cnt2,
                                     unsigned tau, unsigned ngrp) {
    asm volatile("s_waitcnt vmcnt(0)" ::: "memory");   // drain coherent stores
    __syncthreads();
    if (threadIdx.x == 0) {
        unsigned old = __hip_atomic_fetch_add(&cnt1[blockIdx.x >> 4], 1u,
                                              __ATOMIC_RELAXED, __HIP_MEMORY_SCOPE_AGENT);
        if ((old & 15u) == 15u)
            __hip_atomic_fetch_add(cnt2, 1u, __ATOMIC_RELAXED, __HIP_MEMORY_SCOPE_AGENT);
        unsigned target = ngrp * (tau + 1u);
        while (__hip_atomic_load(cnt2, __ATOMIC_RELAXED, __HIP_MEMORY_SCOPE_AGENT) < target)
            __builtin_amdgcn_s_sleep(4);
    }
    __syncthreads();
    asm volatile("" ::: "memory");
}

// ---------------- split f32 -> (hi,lo) bf16 ----------------
__global__ __launch_bounds__(256) void split_f32(const float* __restrict__ src,
                                                 unsigned short* __restrict__ hi,
                                                 unsigned short* __restrict__ lo, int n) {
    int i = blockIdx.x * blockDim.x + threadIdx.x;
    int stride = gridDim.x * blockDim.x;
    for (; i < n; i += stride) {
        float v = src[i];
        unsigned short h = f2bf(v);
        hi[i] = h;
        lo[i] = f2bf(v - bf2f(h));
    }
}

// ---------------- split-bf16 MFMA GEMM (NT) ----------------
__global__ __launch_bounds__(256) void gemm_split(
    const float* __restrict__ A, const int* __restrict__ tokens,
    const unsigned short* __restrict__ Bhi, const unsigned short* __restrict__ Blo,
    const float* __restrict__ bias, float* __restrict__ C,
    int M, int N, int K, int tr96)
{
    __shared__ unsigned short Ah[64][40], Al[64][40];
    __shared__ unsigned short Bh[128][40], Bl[128][40];

    int t = threadIdx.x;
    int m0 = blockIdx.x * 64, n0 = blockIdx.y * 128;
    int wave = t >> 6, lane = t & 63;
    int wm = wave >> 1, wn = wave & 1;
    int kg = lane >> 4, r16 = lane & 15;

    f32x4 acc[2][4];
#pragma unroll
    for (int i = 0; i < 2; i++)
#pragma unroll
        for (int j = 0; j < 4; j++)
#pragma unroll
            for (int q = 0; q < 4; q++) acc[i][j][q] = 0.f;

    int ar = t >> 2, ac8 = (t & 3) * 8;
    long arow = -1;
    if (m0 + ar < M) arow = tokens ? (long)tokens[m0 + ar] : (long)(m0 + ar);

    for (int kt = 0; kt < K; kt += 32) {
        {
            short8 hv, lv;
            if (arow >= 0) {
                const float* ap = A + arow * (long)K + kt + ac8;
                f32x4 u0 = *(const f32x4*)ap;
                f32x4 u1 = *(const f32x4*)(ap + 4);
#pragma unroll
                for (int i = 0; i < 8; i++) {
                    float x = (i < 4) ? u0[i] : u1[i - 4];
                    unsigned short hb = f2bf(x);
                    hv[i] = (short)hb;
                    lv[i] = (short)f2bf(x - bf2f(hb));
                }
            } else {
#pragma unroll
                for (int i = 0; i < 8; i++) { hv[i] = 0; lv[i] = 0; }
            }
            *(short8*)&Ah[ar][ac8] = hv;
            *(short8*)&Al[ar][ac8] = lv;
        }
#pragma unroll
        for (int i = 0; i < 2; i++) {
            int idx = t + i * 256;
            int br = idx >> 2, bc8 = (idx & 3) * 8;
            long go = (long)(n0 + br) * K + kt + bc8;
            *(short8*)&Bh[br][bc8] = *(const short8*)(Bhi + go);
            *(short8*)&Bl[br][bc8] = *(const short8*)(Blo + go);
        }
        __syncthreads();

        short8 afh[2], afl[2], bfh[4], bfl[4];
#pragma unroll
        for (int m16 = 0; m16 < 2; m16++) {
            afh[m16] = *(short8*)&Ah[wm * 32 + m16 * 16 + r16][kg * 8];
            afl[m16] = *(short8*)&Al[wm * 32 + m16 * 16 + r16][kg * 8];
        }
#pragma unroll
        for (int n16 = 0; n16 < 4; n16++) {
            bfh[n16] = *(short8*)&Bh[wn * 64 + n16 * 16 + r16][kg * 8];
            bfl[n16] = *(short8*)&Bl[wn * 64 + n16 * 16 + r16][kg * 8];
        }
#pragma unroll
        for (int m16 = 0; m16 < 2; m16++)
#pragma unroll
            for (int n16 = 0; n16 < 4; n16++) {
                acc[m16][n16] = mfma16(afh[m16], bfh[n16], acc[m16][n16]);
                acc[m16][n16] = mfma16(afh[m16], bfl[n16], acc[m16][n16]);
                acc[m16][n16] = mfma16(afl[m16], bfh[n16], acc[m16][n16]);
            }
        __syncthreads();
    }

#pragma unroll
    for (int m16 = 0; m16 < 2; m16++)
#pragma unroll
        for (int n16 = 0; n16 < 4; n16++)
#pragma unroll
            for (int q = 0; q < 4; q++) {
                int row = m0 + wm * 32 + m16 * 16 + kg * 4 + q;
                int col = n0 + wn * 64 + n16 * 16 + r16;
                if (row < M) {
                    long crow = tr96 ? (long)((row % 96) * 96 + row / 96) : (long)row;
                    C[crow * N + col] = acc[m16][n16][q] + bias[col];
                }
            }
}

// ---------------- persistent word bi-GRU (R8 structure + ablation modes) ----
// 256 blocks x 768 thr. mode 0: barrier only. mode 1: +K-loop+stores (reads
// hread = xWt stand-in). mode 2: real (hread = bi).
__global__ __launch_bounds__(768) void word_rnn(
    const unsigned short* __restrict__ Whi, const unsigned short* __restrict__ Wlo,
    const float* __restrict__ hread,
    const float* __restrict__ xWt,   // [96 pos][96 s][3072]
    const float* __restrict__ bhh, float* __restrict__ bi,
    unsigned* cnt1, unsigned* cnt2, int mode, int nsteps)
{
    __shared__ unsigned short Wh[2][128][24][8];    // 96KB
    __shared__ float psum[6][64][9];                // padded

    int t = threadIdx.x;
    int blk = blockIdx.x;
    int msplit = blk >> 7;
    int j0 = (blk & 127) * 8;
    int wv = t >> 6;                  // 0..11
    int w6 = wv % 6, kq = wv / 6;     // m-tile, K-half
    int lane = t & 63, kg4 = lane >> 4, r16 = lane & 15;
    int wstart = blk & 15;            // per-block window rotation

    for (int i = t; i < 4096; i += 768) {
        int kg = i >> 5, br = i & 31;
        if (br < 24) {
            long src = (long)((br >> 3) * 1024 + j0 + (br & 7)) * 1024 + kg * 8;
            *(short8*)&Wh[0][kg][br][0] = *(const short8*)(Whi + src);
            *(short8*)&Wh[1][kg][br][0] = *(const short8*)(Wlo + src);
        }
    }
    __syncthreads();

    int jj = r16 & 7;
    int j = j0 + jj;
    float b_r = bhh[j], b_z = bhh[1024 + j], b_n = bhh[2048 + j];
    int s_frag = w6 * 16 + r16;
    int kbase = kq * 16;

    f32x4 A0a, A0b, A1a, A1b, A2a, A2b, A3a, A3b;
    f32x4 A4a, A4b, A5a, A5b, A6a, A6b, A7a, A7b;

#define KOFF(i) (kbase + ((wstart + (i)) & 15))

#define LDW(Xa, Xb, i)                                                    \
    do {                                                                  \
        const float* ap = abase + KOFF(i) * 32;                           \
        Xa = *(const f32x4*)ap;                                           \
        Xb = *(const f32x4*)(ap + 4);                                     \
    } while (0)

#define DOW(Xa, Xb, i, P)                                                 \
    do {                                                                  \
        short8 ah, al;                                                    \
        split_win(Xa, Xb, &ah, &al);                                      \
        int kgB = KOFF(i) * 4 + kg4;                                      \
        short8 b0h = *(short8*)&Wh[0][kgB][r16][0];                       \
        short8 b0l = *(short8*)&Wh[1][kgB][r16][0];                       \
        short8 b1h = *(short8*)&Wh[0][kgB][16 + jj][0];                   \
        short8 b1l = *(short8*)&Wh[1][kgB][16 + jj][0];                   \
        acc0##P = mfma16(ah, b0h, acc0##P);                               \
        acc0##P = mfma16(ah, b0l, acc0##P);                               \
        acc0##P = mfma16(al, b0h, acc0##P);                               \
        acc1##P = mfma16(ah, b1h, acc1##P);                               \
        acc1##P = mfma16(ah, b1l, acc1##P);                               \
        acc1##P = mfma16(al, b1h, acc1##P);                               \
    } while (0)

    for (int tau = 0; tau < nsteps; tau++) {
        int pos  = msplit ? (95 - tau) : tau;
        int posp = msplit ? (96 - tau) : (tau - 1);

        if (mode > 0) {
            const float* abase = hread + ((long)s_frag * 96 + posp) * 2048 + msplit * 1024 + kg4 * 8;

            f32x4 acc0A, acc0B, acc1A, acc1B;
#pragma unroll
            for (int q = 0; q < 4; q++) { acc0A[q] = 0.f; acc0B[q] = 0.f; acc1A[q] = 0.f; acc1B[q] = 0.f; }

            float xwv[4][3];
            float hpv[4];
#pragma unroll
            for (int q = 0; q < 4; q++) {
                if (mode == 2 && kq == 0 && r16 < 8) {
                    int hloc = w6 * 16 + kg4 * 4 + q;
                    const float* xp = xWt + ((long)pos * 96 + hloc) * 3072 + j;
                    xwv[q][0] = xp[0];
                    xwv[q][1] = xp[1024];
                    xwv[q][2] = xp[2048];
                    hpv[q] = (tau > 0) ? hread[((long)hloc * 96 + posp) * 2048 + msplit * 1024 + j] : 0.f;
                } else {
                    xwv[q][0] = xwv[q][1] = xwv[q][2] = 0.f;
                    hpv[q] = 0.f;
                }
            }

            if (tau > 0) {
                LDW(A0a, A0b, 0); LDW(A1a, A1b, 1); LDW(A2a, A2b, 2); LDW(A3a, A3b, 3);
                LDW(A4a, A4b, 4); LDW(A5a, A5b, 5); LDW(A6a, A6b, 6); LDW(A7a, A7b, 7);
                DOW(A0a, A0b, 0, A);  LDW(A0a, A0b,  8);
                DOW(A1a, A1b, 1, B);  LDW(A1a, A1b,  9);
                DOW(A2a, A2b, 2, A);  LDW(A2a, A2b, 10);
                DOW(A3a, A3b, 3, B);  LDW(A3a, A3b, 11);
                DOW(A4a, A4b, 4, A);  LDW(A4a, A4b, 12);
                DOW(A5a, A5b, 5, B);  LDW(A5a, A5b, 13);
                DOW(A6a, A6b, 6, A);  LDW(A6a, A6b, 14);
                DOW(A7a, A7b, 7, B);  LDW(A7a, A7b, 15);
                DOW(A0a, A0b,  8, A);
                DOW(A1a, A1b,  9, B);
                DOW(A2a, A2b, 10, A);
                DOW(A3a, A3b, 11, B);
                DOW(A4a, A4b, 12, A);
                DOW(A5a, A5b, 13, B);
                DOW(A6a, A6b, 14, A);
                DOW(A7a, A7b, 15, B);
            }

            if (kq == 1) {
#pragma unroll
                for (int q = 0; q < 4; q++) {
                    psum[w6][lane][q]     = acc0A[q] + acc0B[q];
                    psum[w6][lane][4 + q] = acc1A[q] + acc1B[q];
                }
            }
            __syncthreads();

            if (kq == 0) {
#pragma unroll
                for (int q = 0; q < 4; q++) {
                    float g0 = acc0A[q] + acc0B[q] + psum[w6][lane][q];
                    float g2 = acc1A[q] + acc1B[q] + psum[w6][lane][4 + q];
                    float g1 = __shfl_xor(g0, 8);
                    if (r16 < 8) {
                        int hloc = w6 * 16 + kg4 * 4 + q;
                        float hnew;
                        if (mode == 2) {
                            float rr = sigmoidf_(xwv[q][0] + g0 + b_r);
                            float zz = sigmoidf_(xwv[q][1] + g1 + b_z);
                            float nn = tanhf(xwv[q][2] + rr * (g2 + b_n));
                            hnew = (1.f - zz) * nn + zz * hpv[q];
                        } else {
                            hnew = g0 + g1 + g2;
                        }
                        st_coh(bi + ((long)hloc * 96 + pos) * 2048 + msplit * 1024 + j, hnew);
                    }
                }
            }
        }

        if (tau != nsteps - 1) gbar(cnt1, cnt2, tau, 16);
    }
#undef KOFF
#undef LDW
#undef DOW
}

// ---------------- word attention ----------------
__global__ __launch_bounds__(256) void wscore(
    const float* __restrict__ bi, const float* __restrict__ wctx,
    const float* __restrict__ wctx_b, float* __restrict__ wsc)
{
    int tok = blockIdx.x * 4 + (threadIdx.x >> 6);
    int lane = threadIdx.x & 63;
    const float* row = bi + (long)tok * 2048 + lane * 32;
    const float* cp = wctx + lane * 32;
    float p = 0.f;
#pragma unroll
    for (int i = 0; i < 32; i += 4) {
        f32x4 v = *(const f32x4*)(row + i);
        f32x4 c = *(const f32x4*)(cp + i);
        p += v[0] * c[0] + v[1] * c[1] + v[2] * c[2] + v[3] * c[3];
    }
    p += __shfl_xor(p, 32); p += __shfl_xor(p, 16); p += __shfl_xor(p, 8);
    p += __shfl_xor(p, 4);  p += __shfl_xor(p, 2);  p += __shfl_xor(p, 1);
    if (lane == 0) wsc[tok] = expf(p + wctx_b[0]);
}

__global__ __launch_bounds__(256) void wsum(
    const float* __restrict__ bi, const float* __restrict__ wsc,
    float* __restrict__ sent_vecs)
{
    int s = blockIdx.x;
    int c = blockIdx.y * 256 + threadIdx.x;
    float acc = 0.f;
    for (int tk = 0; tk < 96; tk++)
        acc += wsc[s * 96 + tk] * bi[((long)s * 96 + tk) * 2048 + c];
    sent_vecs[(long)s * 2048 + c] = acc;
}

// ---------------- persistent sentence bi-GRU (fresh-address coherence) ------
__global__ __launch_bounds__(256) void sent_rnn(
    const float* __restrict__ sWhh, const float* __restrict__ xWs,
    const float* __restrict__ sbhh, float* __restrict__ sbi,
    unsigned* cnt1, unsigned* cnt2)
{
    __shared__ float Wl[24 * 1028];
    __shared__ float hsh[2048];
    __shared__ float part[4][48];

    int t = threadIdx.x;
    int j0 = blockIdx.x * 8;
    int w = t >> 6, lane = t & 63;

    for (int i = t; i < 24 * 1024; i += 256) {
        int row = i >> 10, k = i & 1023;
        Wl[row * 1028 + k] = sWhh[(long)((row >> 3) * 1024 + j0 + (row & 7)) * 1024 + k];
    }

    for (int tau = 0; tau < 96; tau++) {
        int posp0 = tau - 1, posp1 = 96 - tau;
        __syncthreads();
        for (int i = t; i < 2048; i += 256) {
            int bq = i >> 10, k = i & 1023;
            int pp = bq ? posp1 : posp0;
            hsh[i] = (tau > 0) ? sbi[(long)pp * 2048 + bq * 1024 + k] : 0.f;
        }
        __syncthreads();

        if (lane < 48) {
            int row = lane >> 1, bq = lane & 1;
            const float* wp = &Wl[row * 1028 + w * 256];
            const float* hp = &hsh[bq * 1024 + w * 256];
            float accd = 0.f;
            for (int k = 0; k < 256; k += 4) {
                f32x4 wv = *(const f32x4*)(wp + k);
                f32x4 hv = *(const f32x4*)(hp + k);
                accd += wv[0] * hv[0] + wv[1] * hv[1] + wv[2] * hv[2] + wv[3] * hv[3];
            }
            part[w][lane] = accd;
        }
        __syncthreads();

        if (t < 16) {
            int jl2 = t >> 1, bq = t & 1;
            int jv = j0 + jl2;
            int pos = bq ? (95 - tau) : tau;
            int pp  = bq ? posp1 : posp0;
            const float* xp = xWs + (long)pos * 3072;
            int d0 = (0 * 8 + jl2) * 2 + bq;
            int d1 = (1 * 8 + jl2) * 2 + bq;
            int d2 = (2 * 8 + jl2) * 2 + bq;
            float D0 = part[0][d0] + part[1][d0] + part[2][d0] + part[3][d0];
            float D1 = part[0][d1] + part[1][d1] + part[2][d1] + part[3][d1];
            float D2 = part[0][d2] + part[1][d2] + part[2][d2] + part[3][d2];
            float rr = sigmoidf_(xp[jv] + D0 + sbhh[jv]);
            float zz = sigmoidf_(xp[1024 + jv] + D1 + sbhh[1024 + jv]);
            float nn = tanhf(xp[2048 + jv] + rr * (D2 + sbhh[2048 + jv]));
            float hprev = (tau > 0) ? sbi[(long)pp * 2048 + bq * 1024 + jv] : 0.f;
            float hnew = (1.f - zz) * nn + zz * hprev;
            st_coh(sbi + (long)pos * 2048 + bq * 1024 + jv, hnew);
        }

        if (tau != 95) gbar(cnt1, cnt2, tau, 8);
    }
}

// ---------------- sentence attention ----------------
__global__ __launch_bounds__(256) void sent_scores(
    const float* __restrict__ sbi, const float* __restrict__ sctx,
    const float* __restrict__ sctx_b, float* __restrict__ scores)
{
    __shared__ float red[4];
    int s = blockIdx.x, t = threadIdx.x, c = t * 8;
    const float* row = sbi + (long)s * 2048 + c;
    float p = 0.f;
#pragma unroll
    for (int i = 0; i < 8; i++) p += row[i] * sctx[c + i];
    p += __shfl_xor(p, 32); p += __shfl_xor(p, 16); p += __shfl_xor(p, 8);
    p += __shfl_xor(p, 4);  p += __shfl_xor(p, 2);  p += __shfl_xor(p, 1);
    int lane = t & 63, w = t >> 6;
    if (lane == 0) red[w] = p;
    __syncthreads();
    if (t == 0) scores[s] = expf(red[0] + red[1] + red[2] + red[3] + sctx_b[0]);
}

__global__ __launch_bounds__(256) void doc_out(
    const float* __restrict__ sbi, const float* __restrict__ scores,
    float* __restrict__ out)
{
    int t = threadIdx.x, c = t * 8;
    float acc[8];
#pragma unroll
    for (int i = 0; i < 8; i++) acc[i] = 0.f;
    for (int s = 0; s < 96; s++) {
        float sc = scores[s];
        const float* row = sbi + (long)s * 2048 + c;
#pragma unroll
        for (int i = 0; i < 8; i++) acc[i] += sc * row[i];
    }
#pragma unroll
    for (int i = 0; i < 8; i++) out[c + i] = acc[i];
}

// ---------------- host ----------------
extern "C" void kernel_launch(void* const* d_in, const int* in_sizes, int n_in,
                              void* d_out, int out_size, void* d_ws, size_t ws_size,
                              hipStream_t stream)
{
    const int*   tokens    = (const int*)  d_in[0];
    const float* embedding = (const float*)d_in[1];
    const float* wWih = (const float*)d_in[2];
    const float* wWhh = (const float*)d_in[3];
    const float* wbih = (const float*)d_in[4];
    const float* wbhh = (const float*)d_in[5];
    const float* sWih = (const float*)d_in[6];
    const float* sWhh = (const float*)d_in[7];
    const float* sbih = (const float*)d_in[8];
    const float* sbhh = (const float*)d_in[9];
    const float* wctxw = (const float*)d_in[10];
    const float* wctxb = (const float*)d_in[11];
    const float* sctxw = (const float*)d_in[12];
    const float* sctxb = (const float*)d_in[13];
    float* out = (float*)d_out;

    char* p = (char*)d_ws;
    auto alloc = [&](size_t bytes) -> char* {
        char* r = p;
        p += (bytes + 255) & ~(size_t)255;
        return r;
    };
    unsigned short* WihHi  = (unsigned short*)alloc(3072l * 1024 * 2);
    unsigned short* WihLo  = (unsigned short*)alloc(3072l * 1024 * 2);
    unsigned short* WhhHi  = (unsigned short*)alloc(3072l * 1024 * 2);
    unsigned short* WhhLo  = (unsigned short*)alloc(3072l * 1024 * 2);
    unsigned short* sWihHi = (unsigned short*)alloc(3072l * 2048 * 2);
    unsigned short* sWihLo = (unsigned short*)alloc(3072l * 2048 * 2);
    float* xWt       = (float*)alloc(9216l * 3072 * 4);   // [pos][s][3072]
    float* bi        = (float*)alloc(9216l * 2048 * 4);   // also word h state
    float* sent_vecs = (float*)alloc(96l * 2048 * 4);
    float* xWs       = (float*)alloc(96l * 3072 * 4);
    float* sbi       = (float*)alloc(96l * 2048 * 4);     // also sent h state
    float* scores    = (float*)alloc(512);
    float* wsc       = (float*)alloc(9216l * 4);
    unsigned* barbuf = (unsigned*)alloc(512);
    (void)ws_size; (void)in_sizes; (void)n_in; (void)out_size;

    hipMemsetAsync(barbuf, 0, 512, stream);

    split_f32<<<1024, 256, 0, stream>>>(wWih, WihHi, WihLo, 3072 * 1024);
    split_f32<<<1024, 256, 0, stream>>>(wWhh, WhhHi, WhhLo, 3072 * 1024);
    split_f32<<<1024, 256, 0, stream>>>(sWih, sWihHi, sWihLo, 3072 * 2048);

    // word input projection, stored transposed: xWt[pos][s][3072]
    gemm_split<<<dim3(144, 24), 256, 0, stream>>>(
        embedding, tokens, WihHi, WihLo, wbih, xWt, 9216, 3072, 1024, 1);

    // ===== ABLATION: V1 barrier-only (32 steps), V2 K-loop (32 steps) =====
    word_rnn<<<256, 768, 0, stream>>>(
        WhhHi, WhhLo, xWt, xWt, wbhh, bi, barbuf + 0, barbuf + 16, 0, 32);
    word_rnn<<<256, 768, 0, stream>>>(
        WhhHi, WhhLo, xWt, xWt, wbhh, bi, barbuf + 20, barbuf + 36, 1, 32);

    // ===== REAL persistent word bi-GRU (96 steps, h state in bi) =====
    word_rnn<<<256, 768, 0, stream>>>(
        WhhHi, WhhLo, bi, xWt, wbhh, bi, barbuf + 40, barbuf + 56, 2, 96);

    // word attention
    wscore<<<2304, 256, 0, stream>>>(bi, wctxw, wctxb, wsc);
    wsum<<<dim3(96, 8), 256, 0, stream>>>(bi, wsc, sent_vecs);

    // sentence input projection: xWs[pos][3072]
    gemm_split<<<dim3(2, 24), 256, 0, stream>>>(
        sent_vecs, nullptr, sWihHi, sWihLo, sbih, xWs, 96, 3072, 2048, 0);

    // persistent sentence bi-GRU
    sent_rnn<<<128, 256, 0, stream>>>(
        sWhh, xWs, sbhh, sbi, barbuf + 64, barbuf + 80);

    sent_scores<<<96, 256, 0, stream>>>(sbi, sctxw, sctxb, scores);
    doc_out<<<1, 256, 0, stream>>>(sbi, scores, out);
}

// Round 10
// 3187.971 us; speedup vs baseline: 1.4620x; 1.4620x over previous
//
#include <hip/hip_runtime.h>
#include <hip/hip_bf16.h>
#include <math.h>

// HAN: word bi-GRU + attention -> sentence bi-GRU + attention -> doc vector.
// R10: tree barrier (per-group flag lines, 8 root pollers) + independent
// fwd/bwd barrier domains. Diagnostic: 96-step barrier-only dispatch at end
// (ranks in top-5 -> prices the barrier directly next round).

typedef __attribute__((ext_vector_type(8))) short short8;
typedef __attribute__((ext_vector_type(4))) float f32x4;

__device__ __forceinline__ unsigned short f2bf(float f) {
    unsigned int u = __float_as_uint(f);
    u += 0x7fff + ((u >> 16) & 1);   // RNE
    return (unsigned short)(u >> 16);
}
__device__ __forceinline__ float bf2f(unsigned short u) {
    return __uint_as_float(((unsigned int)u) << 16);
}
__device__ __forceinline__ float sigmoidf_(float x) { return 1.f / (1.f + expf(-x)); }

__device__ __forceinline__ f32x4 mfma16(short8 a, short8 b, f32x4 c) {
    return __builtin_amdgcn_mfma_f32_16x16x32_bf16(a, b, c, 0, 0, 0);
}

// trunc-split 8 f32 -> hi/lo bf16 short8 (pure bit ops)
__device__ __forceinline__ void split_win(f32x4 a, f32x4 b, short8* hv, short8* lv) {
    union { short8 s; unsigned u[4]; } H, L;
#pragma unroll
    for (int d = 0; d < 4; d++) {
        float f0 = (d < 2) ? a[2 * d] : b[2 * d - 4];
        float f1 = (d < 2) ? a[2 * d + 1] : b[2 * d - 3];
        unsigned u0 = __float_as_uint(f0), u1 = __float_as_uint(f1);
        H.u[d] = (u1 & 0xffff0000u) | (u0 >> 16);
        float l0 = f0 - __uint_as_float(u0 & 0xffff0000u);
        float l1 = f1 - __uint_as_float(u1 & 0xffff0000u);
        L.u[d] = (__float_as_uint(l1) & 0xffff0000u) | (__float_as_uint(l0) >> 16);
    }
    *hv = H.s; *lv = L.s;
}

// coherent (IF-direct) f32 store, relaxed
__device__ __forceinline__ void st_coh(float* p, float v) {
    __hip_atomic_store((unsigned*)p, __float_as_uint(v),
                       __ATOMIC_RELAXED, __HIP_MEMORY_SCOPE_AGENT);
}

// Tree barrier for a 128-block domain (8 groups of 16). Monotonic counters,
// all relaxed, no cache maintenance. Per-line poller counts: root=8, flag<=15.
// Layout in base[]: grp_cnt g at +g*16, root at +128, flag g at +144+g*16.
__device__ __forceinline__ void gbar_tree(unsigned* base, unsigned tau, int dblk) {
    asm volatile("s_waitcnt vmcnt(0)" ::: "memory");   // drain coherent stores
    __syncthreads();
    if (threadIdx.x == 0) {
        int g = dblk >> 4;
        unsigned* gcnt = base + g * 16;
        unsigned* root = base + 128;
        unsigned* flag = base + 144 + g * 16;
        unsigned old = __hip_atomic_fetch_add(gcnt, 1u, __ATOMIC_RELAXED, __HIP_MEMORY_SCOPE_AGENT);
        if ((old & 15u) == 15u)
            __hip_atomic_fetch_add(root, 1u, __ATOMIC_RELAXED, __HIP_MEMORY_SCOPE_AGENT);
        if ((dblk & 15) == 0) {
            unsigned target = 8u * (tau + 1u);
            while (__hip_atomic_load(root, __ATOMIC_RELAXED, __HIP_MEMORY_SCOPE_AGENT) < target)
                __builtin_amdgcn_s_sleep(8);
            __hip_atomic_store(flag, tau + 1u, __ATOMIC_RELAXED, __HIP_MEMORY_SCOPE_AGENT);
        } else {
            while (__hip_atomic_load(flag, __ATOMIC_RELAXED, __HIP_MEMORY_SCOPE_AGENT) < tau + 1u)
                __builtin_amdgcn_s_sleep(8);
        }
    }
    __syncthreads();
    asm volatile("" ::: "memory");
}

// ---------------- split f32 -> (hi,lo) bf16 ----------------
__global__ __launch_bounds__(256) void split_f32(const float* __restrict__ src,
                                                 unsigned short* __restrict__ hi,
                                                 unsigned short* __restrict__ lo, int n) {
    int i = blockIdx.x * blockDim.x + threadIdx.x;
    int stride = gridDim.x * blockDim.x;
    for (; i < n; i += stride) {
        float v = src[i];
        unsigned short h = f2bf(v);
        hi[i] = h;
        lo[i] = f2bf(v - bf2f(h));
    }
}

// ---------------- split-bf16 MFMA GEMM (NT) ----------------
__global__ __launch_bounds__(256) void gemm_split(
    const float* __restrict__ A, const int* __restrict__ tokens,
    const unsigned short* __restrict__ Bhi, const unsigned short* __restrict__ Blo,
    const float* __restrict__ bias, float* __restrict__ C,
    int M, int N, int K, int tr96)
{
    __shared__ unsigned short Ah[64][40], Al[64][40];
    __shared__ unsigned short Bh[128][40], Bl[128][40];

    int t = threadIdx.x;
    int m0 = blockIdx.x * 64, n0 = blockIdx.y * 128;
    int wave = t >> 6, lane = t & 63;
    int wm = wave >> 1, wn = wave & 1;
    int kg = lane >> 4, r16 = lane & 15;

    f32x4 acc[2][4];
#pragma unroll
    for (int i = 0; i < 2; i++)
#pragma unroll
        for (int j = 0; j < 4; j++)
#pragma unroll
            for (int q = 0; q < 4; q++) acc[i][j][q] = 0.f;

    int ar = t >> 2, ac8 = (t & 3) * 8;
    long arow = -1;
    if (m0 + ar < M) arow = tokens ? (long)tokens[m0 + ar] : (long)(m0 + ar);

    for (int kt = 0; kt < K; kt += 32) {
        {
            short8 hv, lv;
            if (arow >= 0) {
                const float* ap = A + arow * (long)K + kt + ac8;
                f32x4 u0 = *(const f32x4*)ap;
                f32x4 u1 = *(const f32x4*)(ap + 4);
#pragma unroll
                for (int i = 0; i < 8; i++) {
                    float x = (i < 4) ? u0[i] : u1[i - 4];
                    unsigned short hb = f2bf(x);
                    hv[i] = (short)hb;
                    lv[i] = (short)f2bf(x - bf2f(hb));
                }
            } else {
#pragma unroll
                for (int i = 0; i < 8; i++) { hv[i] = 0; lv[i] = 0; }
            }
            *(short8*)&Ah[ar][ac8] = hv;
            *(short8*)&Al[ar][ac8] = lv;
        }
#pragma unroll
        for (int i = 0; i < 2; i++) {
            int idx = t + i * 256;
            int br = idx >> 2, bc8 = (idx & 3) * 8;
            long go = (long)(n0 + br) * K + kt + bc8;
            *(short8*)&Bh[br][bc8] = *(const short8*)(Bhi + go);
            *(short8*)&Bl[br][bc8] = *(const short8*)(Blo + go);
        }
        __syncthreads();

        short8 afh[2], afl[2], bfh[4], bfl[4];
#pragma unroll
        for (int m16 = 0; m16 < 2; m16++) {
            afh[m16] = *(short8*)&Ah[wm * 32 + m16 * 16 + r16][kg * 8];
            afl[m16] = *(short8*)&Al[wm * 32 + m16 * 16 + r16][kg * 8];
        }
#pragma unroll
        for (int n16 = 0; n16 < 4; n16++) {
            bfh[n16] = *(short8*)&Bh[wn * 64 + n16 * 16 + r16][kg * 8];
            bfl[n16] = *(short8*)&Bl[wn * 64 + n16 * 16 + r16][kg * 8];
        }
#pragma unroll
        for (int m16 = 0; m16 < 2; m16++)
#pragma unroll
            for (int n16 = 0; n16 < 4; n16++) {
                acc[m16][n16] = mfma16(afh[m16], bfh[n16], acc[m16][n16]);
                acc[m16][n16] = mfma16(afh[m16], bfl[n16], acc[m16][n16]);
                acc[m16][n16] = mfma16(afl[m16], bfh[n16], acc[m16][n16]);
            }
        __syncthreads();
    }

#pragma unroll
    for (int m16 = 0; m16 < 2; m16++)
#pragma unroll
        for (int n16 = 0; n16 < 4; n16++)
#pragma unroll
            for (int q = 0; q < 4; q++) {
                int row = m0 + wm * 32 + m16 * 16 + kg * 4 + q;
                int col = n0 + wn * 64 + n16 * 16 + r16;
                if (row < M) {
                    long crow = tr96 ? (long)((row % 96) * 96 + row / 96) : (long)row;
                    C[crow * N + col] = acc[m16][n16][q] + bias[col];
                }
            }
}

// ---------------- persistent word bi-GRU (tree barrier, fwd/bwd domains) ----
// 256 blocks x 768 thr. mode 0: barrier only (diagnostic). mode 2: real.
__global__ __launch_bounds__(768) void word_rnn(
    const unsigned short* __restrict__ Whi, const unsigned short* __restrict__ Wlo,
    const float* __restrict__ hread,
    const float* __restrict__ xWt,   // [96 pos][96 s][3072]
    const float* __restrict__ bhh, float* __restrict__ bi,
    unsigned* barbase, int mode, int nsteps)
{
    __shared__ unsigned short Wh[2][128][24][8];    // 96KB
    __shared__ float psum[6][64][9];                // padded

    int t = threadIdx.x;
    int blk = blockIdx.x;
    int msplit = blk >> 7;
    int dblk = blk & 127;
    unsigned* dom = barbase + msplit * 512;
    int j0 = (blk & 127) * 8;
    int wv = t >> 6;                  // 0..11
    int w6 = wv % 6, kq = wv / 6;     // m-tile, K-half
    int lane = t & 63, kg4 = lane >> 4, r16 = lane & 15;
    int wstart = blk & 15;            // per-block window rotation

    for (int i = t; i < 4096; i += 768) {
        int kg = i >> 5, br = i & 31;
        if (br < 24) {
            long src = (long)((br >> 3) * 1024 + j0 + (br & 7)) * 1024 + kg * 8;
            *(short8*)&Wh[0][kg][br][0] = *(const short8*)(Whi + src);
            *(short8*)&Wh[1][kg][br][0] = *(const short8*)(Wlo + src);
        }
    }
    __syncthreads();

    int jj = r16 & 7;
    int j = j0 + jj;
    float b_r = bhh[j], b_z = bhh[1024 + j], b_n = bhh[2048 + j];
    int s_frag = w6 * 16 + r16;
    int kbase = kq * 16;

    f32x4 A0a, A0b, A1a, A1b, A2a, A2b, A3a, A3b;
    f32x4 A4a, A4b, A5a, A5b, A6a, A6b, A7a, A7b;

#define KOFF(i) (kbase + ((wstart + (i)) & 15))

#define LDW(Xa, Xb, i)                                                    \
    do {                                                                  \
        const float* ap = abase + KOFF(i) * 32;                           \
        Xa = *(const f32x4*)ap;                                           \
        Xb = *(const f32x4*)(ap + 4);                                     \
    } while (0)

#define DOW(Xa, Xb, i, P)                                                 \
    do {                                                                  \
        short8 ah, al;                                                    \
        split_win(Xa, Xb, &ah, &al);                                      \
        int kgB = KOFF(i) * 4 + kg4;                                      \
        short8 b0h = *(short8*)&Wh[0][kgB][r16][0];                       \
        short8 b0l = *(short8*)&Wh[1][kgB][r16][0];                       \
        short8 b1h = *(short8*)&Wh[0][kgB][16 + jj][0];                   \
        short8 b1l = *(short8*)&Wh[1][kgB][16 + jj][0];                   \
        acc0##P = mfma16(ah, b0h, acc0##P);                               \
        acc0##P = mfma16(ah, b0l, acc0##P);                               \
        acc0##P = mfma16(al, b0h, acc0##P);                               \
        acc1##P = mfma16(ah, b1h, acc1##P);                               \
        acc1##P = mfma16(ah, b1l, acc1##P);                               \
        acc1##P = mfma16(al, b1h, acc1##P);                               \
    } while (0)

    for (int tau = 0; tau < nsteps; tau++) {
        int pos  = msplit ? (95 - tau) : tau;
        int posp = msplit ? (96 - tau) : (tau - 1);

        if (mode > 0) {
            const float* abase = hread + ((long)s_frag * 96 + posp) * 2048 + msplit * 1024 + kg4 * 8;

            f32x4 acc0A, acc0B, acc1A, acc1B;
#pragma unroll
            for (int q = 0; q < 4; q++) { acc0A[q] = 0.f; acc0B[q] = 0.f; acc1A[q] = 0.f; acc1B[q] = 0.f; }

            float xwv[4][3];
            float hpv[4];
#pragma unroll
            for (int q = 0; q < 4; q++) {
                if (kq == 0 && r16 < 8) {
                    int hloc = w6 * 16 + kg4 * 4 + q;
                    const float* xp = xWt + ((long)pos * 96 + hloc) * 3072 + j;
                    xwv[q][0] = xp[0];
                    xwv[q][1] = xp[1024];
                    xwv[q][2] = xp[2048];
                    hpv[q] = (tau > 0) ? hread[((long)hloc * 96 + posp) * 2048 + msplit * 1024 + j] : 0.f;
                } else {
                    xwv[q][0] = xwv[q][1] = xwv[q][2] = 0.f;
                    hpv[q] = 0.f;
                }
            }

            if (tau > 0) {
                LDW(A0a, A0b, 0); LDW(A1a, A1b, 1); LDW(A2a, A2b, 2); LDW(A3a, A3b, 3);
                LDW(A4a, A4b, 4); LDW(A5a, A5b, 5); LDW(A6a, A6b, 6); LDW(A7a, A7b, 7);
                DOW(A0a, A0b, 0, A);  LDW(A0a, A0b,  8);
                DOW(A1a, A1b, 1, B);  LDW(A1a, A1b,  9);
                DOW(A2a, A2b, 2, A);  LDW(A2a, A2b, 10);
                DOW(A3a, A3b, 3, B);  LDW(A3a, A3b, 11);
                DOW(A4a, A4b, 4, A);  LDW(A4a, A4b, 12);
                DOW(A5a, A5b, 5, B);  LDW(A5a, A5b, 13);
                DOW(A6a, A6b, 6, A);  LDW(A6a, A6b, 14);
                DOW(A7a, A7b, 7, B);  LDW(A7a, A7b, 15);
                DOW(A0a, A0b,  8, A);
                DOW(A1a, A1b,  9, B);
                DOW(A2a, A2b, 10, A);
                DOW(A3a, A3b, 11, B);
                DOW(A4a, A4b, 12, A);
                DOW(A5a, A5b, 13, B);
                DOW(A6a, A6b, 14, A);
                DOW(A7a, A7b, 15, B);
            }

            if (kq == 1) {
#pragma unroll
                for (int q = 0; q < 4; q++) {
                    psum[w6][lane][q]     = acc0A[q] + acc0B[q];
                    psum[w6][lane][4 + q] = acc1A[q] + acc1B[q];
                }
            }
            __syncthreads();

            if (kq == 0) {
#pragma unroll
                for (int q = 0; q < 4; q++) {
                    float g0 = acc0A[q] + acc0B[q] + psum[w6][lane][q];
                    float g2 = acc1A[q] + acc1B[q] + psum[w6][lane][4 + q];
                    float g1 = __shfl_xor(g0, 8);
                    if (r16 < 8) {
                        int hloc = w6 * 16 + kg4 * 4 + q;
                        float rr = sigmoidf_(xwv[q][0] + g0 + b_r);
                        float zz = sigmoidf_(xwv[q][1] + g1 + b_z);
                        float nn = tanhf(xwv[q][2] + rr * (g2 + b_n));
                        float hnew = (1.f - zz) * nn + zz * hpv[q];
                        st_coh(bi + ((long)hloc * 96 + pos) * 2048 + msplit * 1024 + j, hnew);
                    }
                }
            }
        }

        if (tau != nsteps - 1) gbar_tree(dom, tau, dblk);
    }
#undef KOFF
#undef LDW
#undef DOW
}

// ---------------- word attention ----------------
__global__ __launch_bounds__(256) void wscore(
    const float* __restrict__ bi, const float* __restrict__ wctx,
    const float* __restrict__ wctx_b, float* __restrict__ wsc)
{
    int tok = blockIdx.x * 4 + (threadIdx.x >> 6);
    int lane = threadIdx.x & 63;
    const float* row = bi + (long)tok * 2048 + lane * 32;
    const float* cp = wctx + lane * 32;
    float p = 0.f;
#pragma unroll
    for (int i = 0; i < 32; i += 4) {
        f32x4 v = *(const f32x4*)(row + i);
        f32x4 c = *(const f32x4*)(cp + i);
        p += v[0] * c[0] + v[1] * c[1] + v[2] * c[2] + v[3] * c[3];
    }
    p += __shfl_xor(p, 32); p += __shfl_xor(p, 16); p += __shfl_xor(p, 8);
    p += __shfl_xor(p, 4);  p += __shfl_xor(p, 2);  p += __shfl_xor(p, 1);
    if (lane == 0) wsc[tok] = expf(p + wctx_b[0]);
}

__global__ __launch_bounds__(256) void wsum(
    const float* __restrict__ bi, const float* __restrict__ wsc,
    float* __restrict__ sent_vecs)
{
    int s = blockIdx.x;
    int c = blockIdx.y * 256 + threadIdx.x;
    float acc = 0.f;
    for (int tk = 0; tk < 96; tk++)
        acc += wsc[s * 96 + tk] * bi[((long)s * 96 + tk) * 2048 + c];
    sent_vecs[(long)s * 2048 + c] = acc;
}

// ---------------- persistent sentence bi-GRU (tree barrier) ----------------
__global__ __launch_bounds__(256) void sent_rnn(
    const float* __restrict__ sWhh, const float* __restrict__ xWs,
    const float* __restrict__ sbhh, float* __restrict__ sbi,
    unsigned* barbase)
{
    __shared__ float Wl[24 * 1028];
    __shared__ float hsh[2048];
    __shared__ float part[4][48];

    int t = threadIdx.x;
    int j0 = blockIdx.x * 8;
    int w = t >> 6, lane = t & 63;

    for (int i = t; i < 24 * 1024; i += 256) {
        int row = i >> 10, k = i & 1023;
        Wl[row * 1028 + k] = sWhh[(long)((row >> 3) * 1024 + j0 + (row & 7)) * 1024 + k];
    }

    for (int tau = 0; tau < 96; tau++) {
        int posp0 = tau - 1, posp1 = 96 - tau;
        __syncthreads();
        for (int i = t; i < 2048; i += 256) {
            int bq = i >> 10, k = i & 1023;
            int pp = bq ? posp1 : posp0;
            hsh[i] = (tau > 0) ? sbi[(long)pp * 2048 + bq * 1024 + k] : 0.f;
        }
        __syncthreads();

        if (lane < 48) {
            int row = lane >> 1, bq = lane & 1;
            const float* wp = &Wl[row * 1028 + w * 256];
            const float* hp = &hsh[bq * 1024 + w * 256];
            float accd = 0.f;
            for (int k = 0; k < 256; k += 4) {
                f32x4 wv = *(const f32x4*)(wp + k);
                f32x4 hv = *(const f32x4*)(hp + k);
                accd += wv[0] * hv[0] + wv[1] * hv[1] + wv[2] * hv[2] + wv[3] * hv[3];
            }
            part[w][lane] = accd;
        }
        __syncthreads();

        if (t < 16) {
            int jl2 = t >> 1, bq = t & 1;
            int jv = j0 + jl2;
            int pos = bq ? (95 - tau) : tau;
            int pp  = bq ? posp1 : posp0;
            const float* xp = xWs + (long)pos * 3072;
            int d0 = (0 * 8 + jl2) * 2 + bq;
            int d1 = (1 * 8 + jl2) * 2 + bq;
            int d2 = (2 * 8 + jl2) * 2 + bq;
            float D0 = part[0][d0] + part[1][d0] + part[2][d0] + part[3][d0];
            float D1 = part[0][d1] + part[1][d1] + part[2][d1] + part[3][d1];
            float D2 = part[0][d2] + part[1][d2] + part[2][d2] + part[3][d2];
            float rr = sigmoidf_(xp[jv] + D0 + sbhh[jv]);
            float zz = sigmoidf_(xp[1024 + jv] + D1 + sbhh[1024 + jv]);
            float nn = tanhf(xp[2048 + jv] + rr * (D2 + sbhh[2048 + jv]));
            float hprev = (tau > 0) ? sbi[(long)pp * 2048 + bq * 1024 + jv] : 0.f;
            float hnew = (1.f - zz) * nn + zz * hprev;
            st_coh(sbi + (long)pos * 2048 + bq * 1024 + jv, hnew);
        }

        if (tau != 95) gbar_tree(barbase, tau, blockIdx.x);
    }
}

// ---------------- sentence attention ----------------
__global__ __launch_bounds__(256) void sent_scores(
    const float* __restrict__ sbi, const float* __restrict__ sctx,
    const float* __restrict__ sctx_b, float* __restrict__ scores)
{
    __shared__ float red[4];
    int s = blockIdx.x, t = threadIdx.x, c = t * 8;
    const float* row = sbi + (long)s * 2048 + c;
    float p = 0.f;
#pragma unroll
    for (int i = 0; i < 8; i++) p += row[i] * sctx[c + i];
    p += __shfl_xor(p, 32); p += __shfl_xor(p, 16); p += __shfl_xor(p, 8);
    p += __shfl_xor(p, 4);  p += __shfl_xor(p, 2);  p += __shfl_xor(p, 1);
    int lane = t & 63, w = t >> 6;
    if (lane == 0) red[w] = p;
    __syncthreads();
    if (t == 0) scores[s] = expf(red[0] + red[1] + red[2] + red[3] + sctx_b[0]);
}

__global__ __launch_bounds__(256) void doc_out(
    const float* __restrict__ sbi, const float* __restrict__ scores,
    float* __restrict__ out)
{
    int t = threadIdx.x, c = t * 8;
    float acc[8];
#pragma unroll
    for (int i = 0; i < 8; i++) acc[i] = 0.f;
    for (int s = 0; s < 96; s++) {
        float sc = scores[s];
        const float* row = sbi + (long)s * 2048 + c;
#pragma unroll
        for (int i = 0; i < 8; i++) acc[i] += sc * row[i];
    }
#pragma unroll
    for (int i = 0; i < 8; i++) out[c + i] = acc[i];
}

// ---------------- host ----------------
extern "C" void kernel_launch(void* const* d_in, const int* in_sizes, int n_in,
                              void* d_out, int out_size, void* d_ws, size_t ws_size,
                              hipStream_t stream)
{
    const int*   tokens    = (const int*)  d_in[0];
    const float* embedding = (const float*)d_in[1];
    const float* wWih = (const float*)d_in[2];
    const float* wWhh = (const float*)d_in[3];
    const float* wbih = (const float*)d_in[4];
    const float* wbhh = (const float*)d_in[5];
    const float* sWih = (const float*)d_in[6];
    const float* sWhh = (const float*)d_in[7];
    const float* sbih = (const float*)d_in[8];
    const float* sbhh = (const float*)d_in[9];
    const float* wctxw = (const float*)d_in[10];
    const float* wctxb = (const float*)d_in[11];
    const float* sctxw = (const float*)d_in[12];
    const float* sctxb = (const float*)d_in[13];
    float* out = (float*)d_out;

    char* p = (char*)d_ws;
    auto alloc = [&](size_t bytes) -> char* {
        char* r = p;
        p += (bytes + 255) & ~(size_t)255;
        return r;
    };
    unsigned short* WihHi  = (unsigned short*)alloc(3072l * 1024 * 2);
    unsigned short* WihLo  = (unsigned short*)alloc(3072l * 1024 * 2);
    unsigned short* WhhHi  = (unsigned short*)alloc(3072l * 1024 * 2);
    unsigned short* WhhLo  = (unsigned short*)alloc(3072l * 1024 * 2);
    unsigned short* sWihHi = (unsigned short*)alloc(3072l * 2048 * 2);
    unsigned short* sWihLo = (unsigned short*)alloc(3072l * 2048 * 2);
    float* xWt       = (float*)alloc(9216l * 3072 * 4);   // [pos][s][3072]
    float* bi        = (float*)alloc(9216l * 2048 * 4);   // also word h state
    float* sent_vecs = (float*)alloc(96l * 2048 * 4);
    float* xWs       = (float*)alloc(96l * 3072 * 4);
    float* sbi       = (float*)alloc(96l * 2048 * 4);     // also sent h state
    float* scores    = (float*)alloc(512);
    float* wsc       = (float*)alloc(9216l * 4);
    unsigned* barbuf = (unsigned*)alloc(16384);
    (void)ws_size; (void)in_sizes; (void)n_in; (void)out_size;

    hipMemsetAsync(barbuf, 0, 16384, stream);

    split_f32<<<1024, 256, 0, stream>>>(wWih, WihHi, WihLo, 3072 * 1024);
    split_f32<<<1024, 256, 0, stream>>>(wWhh, WhhHi, WhhLo, 3072 * 1024);
    split_f32<<<1024, 256, 0, stream>>>(sWih, sWihHi, sWihLo, 3072 * 2048);

    // word input projection, stored transposed: xWt[pos][s][3072]
    gemm_split<<<dim3(144, 24), 256, 0, stream>>>(
        embedding, tokens, WihHi, WihLo, wbih, xWt, 9216, 3072, 1024, 1);

    // persistent word bi-GRU (real; fwd/bwd tree-barrier domains 0,1)
    word_rnn<<<256, 768, 0, stream>>>(
        WhhHi, WhhLo, bi, xWt, wbhh, bi, barbuf + 0 * 512, 2, 96);

    // word attention
    wscore<<<2304, 256, 0, stream>>>(bi, wctxw, wctxb, wsc);
    wsum<<<dim3(96, 8), 256, 0, stream>>>(bi, wsc, sent_vecs);

    // sentence input projection: xWs[pos][3072]
    gemm_split<<<dim3(2, 24), 256, 0, stream>>>(
        sent_vecs, nullptr, sWihHi, sWihLo, sbih, xWs, 96, 3072, 2048, 0);

    // persistent sentence bi-GRU (tree-barrier domain 2)
    sent_rnn<<<128, 256, 0, stream>>>(
        sWhh, xWs, sbhh, sbi, barbuf + 2 * 512);

    sent_scores<<<96, 256, 0, stream>>>(sbi, sctxw, sctxb, scores);
    doc_out<<<1, 256, 0, stream>>>(sbi, scores, out);

    // ===== DIAGNOSTIC (after output): 96-step barrier-only, domains 3,4 =====
    word_rnn<<<256, 768, 0, stream>>>(
        WhhHi, WhhLo, bi, xWt, wbhh, bi, barbuf + 3 * 512, 0, 96);
}

// Round 11
// 2839.688 us; speedup vs baseline: 1.6413x; 1.1226x over previous
//
#include <hip/hip_runtime.h>
#include <hip/hip_bf16.h>
#include <math.h>

// HAN: word bi-GRU + attention -> sentence bi-GRU + attention -> doc vector.
// R11: word_rnn v7 -- M-rep=2 register blocking (32 rows/wave) halves per-CU
// LDS B-read traffic (the TLP-immune shared serializer); 384 thr, depth-4x2
// pipeline; Wh padded [25]; tree barrier w/ faster wake; diagnostic removed.

typedef __attribute__((ext_vector_type(8))) short short8;
typedef __attribute__((ext_vector_type(4))) float f32x4;

__device__ __forceinline__ unsigned short f2bf(float f) {
    unsigned int u = __float_as_uint(f);
    u += 0x7fff + ((u >> 16) & 1);   // RNE
    return (unsigned short)(u >> 16);
}
__device__ __forceinline__ float bf2f(unsigned short u) {
    return __uint_as_float(((unsigned int)u) << 16);
}
__device__ __forceinline__ float sigmoidf_(float x) { return 1.f / (1.f + expf(-x)); }

__device__ __forceinline__ f32x4 mfma16(short8 a, short8 b, f32x4 c) {
    return __builtin_amdgcn_mfma_f32_16x16x32_bf16(a, b, c, 0, 0, 0);
}

// trunc-split 8 f32 -> hi/lo bf16 short8 (pure bit ops)
__device__ __forceinline__ void split_win(f32x4 a, f32x4 b, short8* hv, short8* lv) {
    union { short8 s; unsigned u[4]; } H, L;
#pragma unroll
    for (int d = 0; d < 4; d++) {
        float f0 = (d < 2) ? a[2 * d] : b[2 * d - 4];
        float f1 = (d < 2) ? a[2 * d + 1] : b[2 * d - 3];
        unsigned u0 = __float_as_uint(f0), u1 = __float_as_uint(f1);
        H.u[d] = (u1 & 0xffff0000u) | (u0 >> 16);
        float l0 = f0 - __uint_as_float(u0 & 0xffff0000u);
        float l1 = f1 - __uint_as_float(u1 & 0xffff0000u);
        L.u[d] = (__float_as_uint(l1) & 0xffff0000u) | (__float_as_uint(l0) >> 16);
    }
    *hv = H.s; *lv = L.s;
}

// coherent (IF-direct) f32 store, relaxed
__device__ __forceinline__ void st_coh(float* p, float v) {
    __hip_atomic_store((unsigned*)p, __float_as_uint(v),
                       __ATOMIC_RELAXED, __HIP_MEMORY_SCOPE_AGENT);
}

// Tree barrier for a 128-block domain (8 groups of 16). Monotonic counters,
// all relaxed, no cache maintenance. Per-line pollers: root=8, flag<=15.
__device__ __forceinline__ void gbar_tree(unsigned* base, unsigned tau, int dblk) {
    asm volatile("s_waitcnt vmcnt(0)" ::: "memory");   // drain coherent stores
    __syncthreads();
    if (threadIdx.x == 0) {
        int g = dblk >> 4;
        unsigned* gcnt = base + g * 16;
        unsigned* root = base + 128;
        unsigned* flag = base + 144 + g * 16;
        unsigned old = __hip_atomic_fetch_add(gcnt, 1u, __ATOMIC_RELAXED, __HIP_MEMORY_SCOPE_AGENT);
        if ((old & 15u) == 15u)
            __hip_atomic_fetch_add(root, 1u, __ATOMIC_RELAXED, __HIP_MEMORY_SCOPE_AGENT);
        if ((dblk & 15) == 0) {
            unsigned target = 8u * (tau + 1u);
            while (__hip_atomic_load(root, __ATOMIC_RELAXED, __HIP_MEMORY_SCOPE_AGENT) < target)
                __builtin_amdgcn_s_sleep(2);
            __hip_atomic_store(flag, tau + 1u, __ATOMIC_RELAXED, __HIP_MEMORY_SCOPE_AGENT);
        } else {
            while (__hip_atomic_load(flag, __ATOMIC_RELAXED, __HIP_MEMORY_SCOPE_AGENT) < tau + 1u)
                __builtin_amdgcn_s_sleep(2);
        }
    }
    __syncthreads();
    asm volatile("" ::: "memory");
}

// ---------------- split f32 -> (hi,lo) bf16 ----------------
__global__ __launch_bounds__(256) void split_f32(const float* __restrict__ src,
                                                 unsigned short* __restrict__ hi,
                                                 unsigned short* __restrict__ lo, int n) {
    int i = blockIdx.x * blockDim.x + threadIdx.x;
    int stride = gridDim.x * blockDim.x;
    for (; i < n; i += stride) {
        float v = src[i];
        unsigned short h = f2bf(v);
        hi[i] = h;
        lo[i] = f2bf(v - bf2f(h));
    }
}

// ---------------- split-bf16 MFMA GEMM (NT) ----------------
__global__ __launch_bounds__(256) void gemm_split(
    const float* __restrict__ A, const int* __restrict__ tokens,
    const unsigned short* __restrict__ Bhi, const unsigned short* __restrict__ Blo,
    const float* __restrict__ bias, float* __restrict__ C,
    int M, int N, int K, int tr96)
{
    __shared__ unsigned short Ah[64][40], Al[64][40];
    __shared__ unsigned short Bh[128][40], Bl[128][40];

    int t = threadIdx.x;
    int m0 = blockIdx.x * 64, n0 = blockIdx.y * 128;
    int wave = t >> 6, lane = t & 63;
    int wm = wave >> 1, wn = wave & 1;
    int kg = lane >> 4, r16 = lane & 15;

    f32x4 acc[2][4];
#pragma unroll
    for (int i = 0; i < 2; i++)
#pragma unroll
        for (int j = 0; j < 4; j++)
#pragma unroll
            for (int q = 0; q < 4; q++) acc[i][j][q] = 0.f;

    int ar = t >> 2, ac8 = (t & 3) * 8;
    long arow = -1;
    if (m0 + ar < M) arow = tokens ? (long)tokens[m0 + ar] : (long)(m0 + ar);

    for (int kt = 0; kt < K; kt += 32) {
        {
            short8 hv, lv;
            if (arow >= 0) {
                const float* ap = A + arow * (long)K + kt + ac8;
                f32x4 u0 = *(const f32x4*)ap;
                f32x4 u1 = *(const f32x4*)(ap + 4);
#pragma unroll
                for (int i = 0; i < 8; i++) {
                    float x = (i < 4) ? u0[i] : u1[i - 4];
                    unsigned short hb = f2bf(x);
                    hv[i] = (short)hb;
                    lv[i] = (short)f2bf(x - bf2f(hb));
                }
            } else {
#pragma unroll
                for (int i = 0; i < 8; i++) { hv[i] = 0; lv[i] = 0; }
            }
            *(short8*)&Ah[ar][ac8] = hv;
            *(short8*)&Al[ar][ac8] = lv;
        }
#pragma unroll
        for (int i = 0; i < 2; i++) {
            int idx = t + i * 256;
            int br = idx >> 2, bc8 = (idx & 3) * 8;
            long go = (long)(n0 + br) * K + kt + bc8;
            *(short8*)&Bh[br][bc8] = *(const short8*)(Bhi + go);
            *(short8*)&Bl[br][bc8] = *(const short8*)(Blo + go);
        }
        __syncthreads();

        short8 afh[2], afl[2], bfh[4], bfl[4];
#pragma unroll
        for (int m16 = 0; m16 < 2; m16++) {
            afh[m16] = *(short8*)&Ah[wm * 32 + m16 * 16 + r16][kg * 8];
            afl[m16] = *(short8*)&Al[wm * 32 + m16 * 16 + r16][kg * 8];
        }
#pragma unroll
        for (int n16 = 0; n16 < 4; n16++) {
            bfh[n16] = *(short8*)&Bh[wn * 64 + n16 * 16 + r16][kg * 8];
            bfl[n16] = *(short8*)&Bl[wn * 64 + n16 * 16 + r16][kg * 8];
        }
#pragma unroll
        for (int m16 = 0; m16 < 2; m16++)
#pragma unroll
            for (int n16 = 0; n16 < 4; n16++) {
                acc[m16][n16] = mfma16(afh[m16], bfh[n16], acc[m16][n16]);
                acc[m16][n16] = mfma16(afh[m16], bfl[n16], acc[m16][n16]);
                acc[m16][n16] = mfma16(afl[m16], bfh[n16], acc[m16][n16]);
            }
        __syncthreads();
    }

#pragma unroll
    for (int m16 = 0; m16 < 2; m16++)
#pragma unroll
        for (int n16 = 0; n16 < 4; n16++)
#pragma unroll
            for (int q = 0; q < 4; q++) {
                int row = m0 + wm * 32 + m16 * 16 + kg * 4 + q;
                int col = n0 + wn * 64 + n16 * 16 + r16;
                if (row < M) {
                    long crow = tr96 ? (long)((row % 96) * 96 + row / 96) : (long)row;
                    C[crow * N + col] = acc[m16][n16][q] + bias[col];
                }
            }
}

// ---------------- persistent word bi-GRU v7 (M-rep=2) ----------------
// 256 blocks x 384 thr (6 waves = 3 m-tiles x 2 K-halves). Each wave: 32 rows
// (2 m16 reps) vs same B fragments -> LDS B-reads halved. Whh hi+lo in LDS
// [arr][kg][25pad][8] (102KB). h state IS bi (fresh address per step).
__global__ __launch_bounds__(384) void word_rnn(
    const unsigned short* __restrict__ Whi, const unsigned short* __restrict__ Wlo,
    const float* __restrict__ xWt,   // [96 pos][96 s][3072]
    const float* __restrict__ bhh, float* __restrict__ bi,
    unsigned* barbase)
{
    __shared__ unsigned short Wh[2][128][25][8];    // 102.4 KB (kg-stride 400B)
    __shared__ float psum[3][64][2][9];             // 13.8 KB

    int t = threadIdx.x;
    int blk = blockIdx.x;
    int msplit = blk >> 7;
    int dblk = blk & 127;
    unsigned* dom = barbase + msplit * 512;
    int j0 = dblk * 8;
    int wv = t >> 6;                  // 0..5
    int w3 = wv % 3, kq = wv / 3;     // m-tile (32 rows), K-half
    int lane = t & 63, kg4 = lane >> 4, r16 = lane & 15;
    int wstart = blk & 15;            // per-block window rotation

    for (int i = t; i < 4096; i += 384) {
        int kg = i >> 5, br = i & 31;
        if (br < 24) {
            long src = (long)((br >> 3) * 1024 + j0 + (br & 7)) * 1024 + kg * 8;
            *(short8*)&Wh[0][kg][br][0] = *(const short8*)(Whi + src);
            *(short8*)&Wh[1][kg][br][0] = *(const short8*)(Wlo + src);
        }
    }
    __syncthreads();

    int jj = r16 & 7;
    int j = j0 + jj;
    float b_r = bhh[j], b_z = bhh[1024 + j], b_n = bhh[2048 + j];
    int sf0 = w3 * 32 + r16;          // row rep 0 (rep 1 = +16)
    int kbase = kq * 16;
    const long ROWSTRIDE = (long)16 * 96 * 2048;   // 16 sentences in bi

    // 4 pipeline slots x 2 rows
    f32x4 X0a, X0b, X1a, X1b, X2a, X2b, X3a, X3b;   // row0
    f32x4 Y0a, Y0b, Y1a, Y1b, Y2a, Y2b, Y3a, Y3b;   // row1

#define KOFF(i) (kbase + ((wstart + (i)) & 15))

#define LDW2(s, i)                                                        \
    do {                                                                  \
        const float* a0 = ab0 + KOFF(i) * 32;                             \
        const float* a1 = ab1 + KOFF(i) * 32;                             \
        X##s##a = *(const f32x4*)a0;  X##s##b = *(const f32x4*)(a0 + 4);  \
        Y##s##a = *(const f32x4*)a1;  Y##s##b = *(const f32x4*)(a1 + 4);  \
    } while (0)

#define DOW2(s, i)                                                        \
    do {                                                                  \
        short8 ah0, al0, ah1, al1;                                        \
        split_win(X##s##a, X##s##b, &ah0, &al0);                          \
        split_win(Y##s##a, Y##s##b, &ah1, &al1);                          \
        int kgB = KOFF(i) * 4 + kg4;                                      \
        short8 b0h = *(short8*)&Wh[0][kgB][r16][0];                       \
        short8 b0l = *(short8*)&Wh[1][kgB][r16][0];                       \
        short8 b1h = *(short8*)&Wh[0][kgB][16 + jj][0];                   \
        short8 b1l = *(short8*)&Wh[1][kgB][16 + jj][0];                   \
        acc00 = mfma16(ah0, b0h, acc00);                                  \
        acc10 = mfma16(ah1, b0h, acc10);                                  \
        acc00 = mfma16(ah0, b0l, acc00);                                  \
        acc10 = mfma16(ah1, b0l, acc10);                                  \
        acc00 = mfma16(al0, b0h, acc00);                                  \
        acc10 = mfma16(al1, b0h, acc10);                                  \
        acc01 = mfma16(ah0, b1h, acc01);                                  \
        acc11 = mfma16(ah1, b1h, acc11);                                  \
        acc01 = mfma16(ah0, b1l, acc01);                                  \
        acc11 = mfma16(ah1, b1l, acc11);                                  \
        acc01 = mfma16(al0, b1h, acc01);                                  \
        acc11 = mfma16(al1, b1h, acc11);                                  \
    } while (0)

    for (int tau = 0; tau < 96; tau++) {
        int pos  = msplit ? (95 - tau) : tau;
        int posp = msplit ? (96 - tau) : (tau - 1);

        const float* ab0 = bi + ((long)sf0 * 96 + posp) * 2048 + msplit * 1024 + kg4 * 8;
        const float* ab1 = ab0 + ROWSTRIDE;

        f32x4 acc00, acc01, acc10, acc11;
#pragma unroll
        for (int q = 0; q < 4; q++) { acc00[q] = 0.f; acc01[q] = 0.f; acc10[q] = 0.f; acc11[q] = 0.f; }

        // epilogue operands (kq==0 producing lanes), retire under K-loop
        float xwv[2][4][3];
        float hpv[2][4];
#pragma unroll
        for (int mi = 0; mi < 2; mi++)
#pragma unroll
            for (int q = 0; q < 4; q++) {
                if (kq == 0 && r16 < 8) {
                    int hloc = w3 * 32 + mi * 16 + kg4 * 4 + q;
                    const float* xp = xWt + ((long)pos * 96 + hloc) * 3072 + j;
                    xwv[mi][q][0] = xp[0];
                    xwv[mi][q][1] = xp[1024];
                    xwv[mi][q][2] = xp[2048];
                    hpv[mi][q] = (tau > 0) ? bi[((long)hloc * 96 + posp) * 2048 + msplit * 1024 + j] : 0.f;
                } else {
                    xwv[mi][q][0] = xwv[mi][q][1] = xwv[mi][q][2] = 0.f;
                    hpv[mi][q] = 0.f;
                }
            }

        if (tau > 0) {
            LDW2(0, 0); LDW2(1, 1); LDW2(2, 2); LDW2(3, 3);
            DOW2(0, 0);  LDW2(0, 4);
            DOW2(1, 1);  LDW2(1, 5);
            DOW2(2, 2);  LDW2(2, 6);
            DOW2(3, 3);  LDW2(3, 7);
            DOW2(0, 4);  LDW2(0, 8);
            DOW2(1, 5);  LDW2(1, 9);
            DOW2(2, 6);  LDW2(2, 10);
            DOW2(3, 7);  LDW2(3, 11);
            DOW2(0, 8);  LDW2(0, 12);
            DOW2(1, 9);  LDW2(1, 13);
            DOW2(2, 10); LDW2(2, 14);
            DOW2(3, 11); LDW2(3, 15);
            DOW2(0, 12);
            DOW2(1, 13);
            DOW2(2, 14);
            DOW2(3, 15);
        }

        // K-half partial exchange
        if (kq == 1) {
#pragma unroll
            for (int q = 0; q < 4; q++) {
                psum[w3][lane][0][q]     = acc00[q];
                psum[w3][lane][0][4 + q] = acc01[q];
                psum[w3][lane][1][q]     = acc10[q];
                psum[w3][lane][1][4 + q] = acc11[q];
            }
        }
        __syncthreads();

        if (kq == 0) {
#pragma unroll
            for (int mi = 0; mi < 2; mi++) {
#pragma unroll
                for (int q = 0; q < 4; q++) {
                    float a0 = (mi == 0) ? acc00[q] : acc10[q];
                    float a1 = (mi == 0) ? acc01[q] : acc11[q];
                    float g0 = a0 + psum[w3][lane][mi][q];
                    float g2 = a1 + psum[w3][lane][mi][4 + q];
                    float g1 = __shfl_xor(g0, 8);
                    if (r16 < 8) {
                        int hloc = w3 * 32 + mi * 16 + kg4 * 4 + q;
                        float rr = sigmoidf_(xwv[mi][q][0] + g0 + b_r);
                        float zz = sigmoidf_(xwv[mi][q][1] + g1 + b_z);
                        float nn = tanhf(xwv[mi][q][2] + rr * (g2 + b_n));
                        float hnew = (1.f - zz) * nn + zz * hpv[mi][q];
                        st_coh(bi + ((long)hloc * 96 + pos) * 2048 + msplit * 1024 + j, hnew);
                    }
                }
            }
        }

        if (tau != 95) gbar_tree(dom, tau, dblk);
    }
#undef KOFF
#undef LDW2
#undef DOW2
}

// ---------------- word attention ----------------
__global__ __launch_bounds__(256) void wscore(
    const float* __restrict__ bi, const float* __restrict__ wctx,
    const float* __restrict__ wctx_b, float* __restrict__ wsc)
{
    int tok = blockIdx.x * 4 + (threadIdx.x >> 6);
    int lane = threadIdx.x & 63;
    const float* row = bi + (long)tok * 2048 + lane * 32;
    const float* cp = wctx + lane * 32;
    float p = 0.f;
#pragma unroll
    for (int i = 0; i < 32; i += 4) {
        f32x4 v = *(const f32x4*)(row + i);
        f32x4 c = *(const f32x4*)(cp + i);
        p += v[0] * c[0] + v[1] * c[1] + v[2] * c[2] + v[3] * c[3];
    }
    p += __shfl_xor(p, 32); p += __shfl_xor(p, 16); p += __shfl_xor(p, 8);
    p += __shfl_xor(p, 4);  p += __shfl_xor(p, 2);  p += __shfl_xor(p, 1);
    if (lane == 0) wsc[tok] = expf(p + wctx_b[0]);
}

__global__ __launch_bounds__(256) void wsum(
    const float* __restrict__ bi, const float* __restrict__ wsc,
    float* __restrict__ sent_vecs)
{
    int s = blockIdx.x;
    int c = blockIdx.y * 256 + threadIdx.x;
    float acc = 0.f;
    for (int tk = 0; tk < 96; tk++)
        acc += wsc[s * 96 + tk] * bi[((long)s * 96 + tk) * 2048 + c];
    sent_vecs[(long)s * 2048 + c] = acc;
}

// ---------------- persistent sentence bi-GRU (tree barrier) ----------------
__global__ __launch_bounds__(256) void sent_rnn(
    const float* __restrict__ sWhh, const float* __restrict__ xWs,
    const float* __restrict__ sbhh, float* __restrict__ sbi,
    unsigned* barbase)
{
    __shared__ float Wl[24 * 1028];
    __shared__ float hsh[2048];
    __shared__ float part[4][48];

    int t = threadIdx.x;
    int j0 = blockIdx.x * 8;
    int w = t >> 6, lane = t & 63;

    for (int i = t; i < 24 * 1024; i += 256) {
        int row = i >> 10, k = i & 1023;
        Wl[row * 1028 + k] = sWhh[(long)((row >> 3) * 1024 + j0 + (row & 7)) * 1024 + k];
    }

    for (int tau = 0; tau < 96; tau++) {
        int posp0 = tau - 1, posp1 = 96 - tau;
        __syncthreads();
        for (int i = t; i < 2048; i += 256) {
            int bq = i >> 10, k = i & 1023;
            int pp = bq ? posp1 : posp0;
            hsh[i] = (tau > 0) ? sbi[(long)pp * 2048 + bq * 1024 + k] : 0.f;
        }
        __syncthreads();

        if (lane < 48) {
            int row = lane >> 1, bq = lane & 1;
            const float* wp = &Wl[row * 1028 + w * 256];
            const float* hp = &hsh[bq * 1024 + w * 256];
            float accd = 0.f;
            for (int k = 0; k < 256; k += 4) {
                f32x4 wv = *(const f32x4*)(wp + k);
                f32x4 hv = *(const f32x4*)(hp + k);
                accd += wv[0] * hv[0] + wv[1] * hv[1] + wv[2] * hv[2] + wv[3] * hv[3];
            }
            part[w][lane] = accd;
        }
        __syncthreads();

        if (t < 16) {
            int jl2 = t >> 1, bq = t & 1;
            int jv = j0 + jl2;
            int pos = bq ? (95 - tau) : tau;
            int pp  = bq ? posp1 : posp0;
            const float* xp = xWs + (long)pos * 3072;
            int d0 = (0 * 8 + jl2) * 2 + bq;
            int d1 = (1 * 8 + jl2) * 2 + bq;
            int d2 = (2 * 8 + jl2) * 2 + bq;
            float D0 = part[0][d0] + part[1][d0] + part[2][d0] + part[3][d0];
            float D1 = part[0][d1] + part[1][d1] + part[2][d1] + part[3][d1];
            float D2 = part[0][d2] + part[1][d2] + part[2][d2] + part[3][d2];
            float rr = sigmoidf_(xp[jv] + D0 + sbhh[jv]);
            float zz = sigmoidf_(xp[1024 + jv] + D1 + sbhh[1024 + jv]);
            float nn = tanhf(xp[2048 + jv] + rr * (D2 + sbhh[2048 + jv]));
            float hprev = (tau > 0) ? sbi[(long)pp * 2048 + bq * 1024 + jv] : 0.f;
            float hnew = (1.f - zz) * nn + zz * hprev;
            st_coh(sbi + (long)pos * 2048 + bq * 1024 + jv, hnew);
        }

        if (tau != 95) gbar_tree(barbase, tau, blockIdx.x);
    }
}

// ---------------- sentence attention ----------------
__global__ __launch_bounds__(256) void sent_scores(
    const float* __restrict__ sbi, const float* __restrict__ sctx,
    const float* __restrict__ sctx_b, float* __restrict__ scores)
{
    __shared__ float red[4];
    int s = blockIdx.x, t = threadIdx.x, c = t * 8;
    const float* row = sbi + (long)s * 2048 + c;
    float p = 0.f;
#pragma unroll
    for (int i = 0; i < 8; i++) p += row[i] * sctx[c + i];
    p += __shfl_xor(p, 32); p += __shfl_xor(p, 16); p += __shfl_xor(p, 8);
    p += __shfl_xor(p, 4);  p += __shfl_xor(p, 2);  p += __shfl_xor(p, 1);
    int lane = t & 63, w = t >> 6;
    if (lane == 0) red[w] = p;
    __syncthreads();
    if (t == 0) scores[s] = expf(red[0] + red[1] + red[2] + red[3] + sctx_b[0]);
}

__global__ __launch_bounds__(256) void doc_out(
    const float* __restrict__ sbi, const float* __restrict__ scores,
    float* __restrict__ out)
{
    int t = threadIdx.x, c = t * 8;
    float acc[8];
#pragma unroll
    for (int i = 0; i < 8; i++) acc[i] = 0.f;
    for (int s = 0; s < 96; s++) {
        float sc = scores[s];
        const float* row = sbi + (long)s * 2048 + c;
#pragma unroll
        for (int i = 0; i < 8; i++) acc[i] += sc * row[i];
    }
#pragma unroll
    for (int i = 0; i < 8; i++) out[c + i] = acc[i];
}

// ---------------- host ----------------
extern "C" void kernel_launch(void* const* d_in, const int* in_sizes, int n_in,
                              void* d_out, int out_size, void* d_ws, size_t ws_size,
                              hipStream_t stream)
{
    const int*   tokens    = (const int*)  d_in[0];
    const float* embedding = (const float*)d_in[1];
    const float* wWih = (const float*)d_in[2];
    const float* wWhh = (const float*)d_in[3];
    const float* wbih = (const float*)d_in[4];
    const float* wbhh = (const float*)d_in[5];
    const float* sWih = (const float*)d_in[6];
    const float* sWhh = (const float*)d_in[7];
    const float* sbih = (const float*)d_in[8];
    const float* sbhh = (const float*)d_in[9];
    const float* wctxw = (const float*)d_in[10];
    const float* wctxb = (const float*)d_in[11];
    const float* sctxw = (const float*)d_in[12];
    const float* sctxb = (const float*)d_in[13];
    float* out = (float*)d_out;

    char* p = (char*)d_ws;
    auto alloc = [&](size_t bytes) -> char* {
        char* r = p;
        p += (bytes + 255) & ~(size_t)255;
        return r;
    };
    unsigned short* WihHi  = (unsigned short*)alloc(3072l * 1024 * 2);
    unsigned short* WihLo  = (unsigned short*)alloc(3072l * 1024 * 2);
    unsigned short* WhhHi  = (unsigned short*)alloc(3072l * 1024 * 2);
    unsigned short* WhhLo  = (unsigned short*)alloc(3072l * 1024 * 2);
    unsigned short* sWihHi = (unsigned short*)alloc(3072l * 2048 * 2);
    unsigned short* sWihLo = (unsigned short*)alloc(3072l * 2048 * 2);
    float* xWt       = (float*)alloc(9216l * 3072 * 4);   // [pos][s][3072]
    float* bi        = (float*)alloc(9216l * 2048 * 4);   // also word h state
    float* sent_vecs = (float*)alloc(96l * 2048 * 4);
    float* xWs       = (float*)alloc(96l * 3072 * 4);
    float* sbi       = (float*)alloc(96l * 2048 * 4);     // also sent h state
    float* scores    = (float*)alloc(512);
    float* wsc       = (float*)alloc(9216l * 4);
    unsigned* barbuf = (unsigned*)alloc(16384);
    (void)ws_size; (void)in_sizes; (void)n_in; (void)out_size;

    hipMemsetAsync(barbuf, 0, 16384, stream);

    split_f32<<<1024, 256, 0, stream>>>(wWih, WihHi, WihLo, 3072 * 1024);
    split_f32<<<1024, 256, 0, stream>>>(wWhh, WhhHi, WhhLo, 3072 * 1024);
    split_f32<<<1024, 256, 0, stream>>>(sWih, sWihHi, sWihLo, 3072 * 2048);

    // word input projection, stored transposed: xWt[pos][s][3072]
    gemm_split<<<dim3(144, 24), 256, 0, stream>>>(
        embedding, tokens, WihHi, WihLo, wbih, xWt, 9216, 3072, 1024, 1);

    // persistent word bi-GRU (fwd/bwd tree-barrier domains 0,1)
    word_rnn<<<256, 384, 0, stream>>>(
        WhhHi, WhhLo, xWt, wbhh, bi, barbuf);

    // word attention
    wscore<<<2304, 256, 0, stream>>>(bi, wctxw, wctxb, wsc);
    wsum<<<dim3(96, 8), 256, 0, stream>>>(bi, wsc, sent_vecs);

    // sentence input projection: xWs[pos][3072]
    gemm_split<<<dim3(2, 24), 256, 0, stream>>>(
        sent_vecs, nullptr, sWihHi, sWihLo, sbih, xWs, 96, 3072, 2048, 0);

    // persistent sentence bi-GRU (tree-barrier domain 2)
    sent_rnn<<<128, 256, 0, stream>>>(
        sWhh, xWs, sbhh, sbi, barbuf + 1024);

    sent_scores<<<96, 256, 0, stream>>>(sbi, sctxw, sctxb, scores);
    doc_out<<<1, 256, 0, stream>>>(sbi, scores, out);
}